// Round 1
// baseline (238.310 us; speedup 1.0000x reference)
//
#include <hip/hip_runtime.h>

// Problem constants (from reference)
#define BATCH 4
#define POINT_NUM 50000
#define NPTS (BATCH * POINT_NUM)   // 200000
#define NVOX 150000
#define FEAT 256

// Fused single pass: one wave (64 lanes) per OUTPUT POINT.
//   lane l loads float4 of the point's voxel feature row at [4l, 4l+4),
//   computes both partial dots against w[0,:] and w[1,:],
//   butterfly-reduces across the wave, lane 0 writes the 2 scores.
//
// Rationale vs the previous 2-pass (project-all-voxels + gather):
//  - touches NO workspace -> the harness's 614 MB workspace poison fill
//    (2 x ~91 us per iteration, the top dispatches in rocprof) is no longer
//    on our account.
//  - only ~111K of 150K voxel rows are actually referenced (Poisson
//    lambda=4/3), so first-touch HBM fetch is ~113 MB < the 153.6 MB full
//    sweep; repeated rows hit L2/L3 (all touched rows fit in 256 MB LLC).
//  - each wave still reads one CONTIGUOUS 1 KB row (float4/lane) -> full
//    coalescing; randomness is only at row granularity.
__global__ __launch_bounds__(256) void fused_score_kernel(
    const float* __restrict__ feat,   // [NVOX, FEAT]
    const int*   __restrict__ idx,    // [NPTS]
    const float* __restrict__ w,      // [2, FEAT]
    const float* __restrict__ bias,   // [2]
    float* __restrict__ out)          // [2, NPTS]
{
    const int wave = (blockIdx.x * blockDim.x + threadIdx.x) >> 6;
    const int lane = threadIdx.x & 63;
    if (wave >= NPTS) return;

    // All 64 lanes read the same idx word -> served by cache broadcast.
    const int v = idx[wave];

    // Weight rows: 2 KB total, L1-resident after first wave.
    const float4 w0 = ((const float4*)(w))[lane];
    const float4 w1 = ((const float4*)(w + FEAT))[lane];

    // 1 KB contiguous gather of the voxel's feature row.
    const float4 f = ((const float4*)(feat + (size_t)v * FEAT))[lane];

    float a = f.x * w0.x + f.y * w0.y + f.z * w0.z + f.w * w0.w;
    float b = f.x * w1.x + f.y * w1.y + f.z * w1.z + f.w * w1.w;

    #pragma unroll
    for (int off = 32; off > 0; off >>= 1) {
        a += __shfl_down(a, off, 64);
        b += __shfl_down(b, off, 64);
    }

    if (lane == 0) {
        out[wave]        = a + bias[0];   // seal_score_pred
        out[NPTS + wave] = b + bias[1];   // wrench_score_pred
    }
}

extern "C" void kernel_launch(void* const* d_in, const int* in_sizes, int n_in,
                              void* d_out, int out_size, void* d_ws, size_t ws_size,
                              hipStream_t stream) {
    const float* feat = (const float*)d_in[0];
    const int*   idx  = (const int*)d_in[1];
    const float* w    = (const float*)d_in[2];
    const float* bias = (const float*)d_in[3];
    float* out = (float*)d_out;

    (void)d_ws; (void)ws_size;  // deliberately unused: no workspace traffic

    // 200000 waves, 4 waves per 256-thread block -> 50000 blocks
    const int blocks = (NPTS * 64 + 255) / 256;
    fused_score_kernel<<<blocks, 256, 0, stream>>>(feat, idx, w, bias, out);
}